// Round 4
// baseline (553.142 us; speedup 1.0000x reference)
//
#include <hip/hip_runtime.h>
#include <math.h>

#define NB   1024
#define LI   2
#define LH   256
#define KK   40
#define IMG  16
#define PW   24   // padded LDS row stride: 4 rows/wave start at banks {0,24,16,8} -> exact 2-way (free)
#define PH   18

// ---------------------------------------------------------------------------
// prep: collapse h-conv + 1x1 r-conv into one effective 2->1 3x3 conv.
// ---------------------------------------------------------------------------
__global__ void prep_kernel(const float* __restrict__ h_w,
                            const float* __restrict__ h_b,
                            const float* __restrict__ r_w,
                            float* __restrict__ weff) {
    int t = threadIdx.x;
    if (t < 19) {
        float acc = 0.f;
        if (t < 18) {
            for (int c = 0; c < LH; ++c)
                acc += r_w[c] * h_w[c * 18 + t];
        } else {
            for (int c = 0; c < LH; ++c)
                acc += r_w[c] * h_b[c];
        }
        weff[t] = acc;
    }
}

// ---------------------------------------------------------------------------
// main: one block per batch image; 256 threads = 16x16 pixels.
// qr[64] resident in VGPRs (launch_bounds(256,2) -> 256-VGPR budget).
// v ping-pongs between two zero-bordered LDS buffers (no runtime base select).
// ---------------------------------------------------------------------------
__global__ __launch_bounds__(256, 2) void vin_kernel(
    const float* __restrict__ X,     const float* __restrict__ S1,
    const float* __restrict__ S2,    const float* __restrict__ gamma,
    const float* __restrict__ q_w,   const float* __restrict__ w,
    const float* __restrict__ fc1,   const float* __restrict__ fc2,
    const float* __restrict__ fc3,   const float* __restrict__ weff,
    float* __restrict__ out) {
    __shared__ float rpad[PH * PW];
    __shared__ float vb0[PH * PW];
    __shared__ float vb1[PH * PW];
    __shared__ float vout[580];
    __shared__ float l1[100];
    __shared__ float l2[52];

    const int b = blockIdx.x;
    const int t = threadIdx.x;
    const int x = t & 15;
    const int y = t >> 4;
    const int tl  = y * PW + x;           // top-left of 3x3 window (padded coords)
    const int ctr = (y + 1) * PW + (x + 1);

    for (int idx = t; idx < PH * PW; idx += 256) {
        rpad[idx] = 0.f;
        vb0[idx]  = 0.f;
        vb1[idx]  = 0.f;
    }
    __syncthreads();

    // ---- r = conv3x3(X, W_eff) + b_eff ----
    const float* Xb = X + (size_t)b * (LI * IMG * IMG);
    float racc = weff[18];
#pragma unroll
    for (int i = 0; i < LI; ++i) {
#pragma unroll
        for (int ky = 0; ky < 3; ++ky) {
            int yy = y + ky - 1;
#pragma unroll
            for (int kx = 0; kx < 3; ++kx) {
                int xx = x + kx - 1;
                if (yy >= 0 && yy < IMG && xx >= 0 && xx < IMG)
                    racc += weff[i * 9 + ky * 3 + kx] * Xb[i * 256 + yy * 16 + xx];
            }
        }
    }
    rpad[ctr] = racc;
    __syncthreads();

    // ---- qr = conv3x3(r, q_w); v0 = max_ch(qr) ----
    float qr[64];
    {
        float p0 = rpad[tl],          p1 = rpad[tl + 1],          p2 = rpad[tl + 2];
        float p3 = rpad[tl + PW],     p4 = rpad[tl + PW + 1],     p5 = rpad[tl + PW + 2];
        float p6 = rpad[tl + 2 * PW], p7 = rpad[tl + 2 * PW + 1], p8 = rpad[tl + 2 * PW + 2];
        float vm = -1e30f;
#pragma unroll
        for (int o = 0; o < 64; ++o) {
            float acc = 0.f;
            acc += q_w[o * 9 + 0] * p0; acc += q_w[o * 9 + 1] * p1; acc += q_w[o * 9 + 2] * p2;
            acc += q_w[o * 9 + 3] * p3; acc += q_w[o * 9 + 4] * p4; acc += q_w[o * 9 + 5] * p5;
            acc += q_w[o * 9 + 6] * p6; acc += q_w[o * 9 + 7] * p7; acc += q_w[o * 9 + 8] * p8;
            qr[o] = acc;
            vm = fmaxf(vm, acc);
        }
        vb0[ctr] = vm;
    }
    __syncthreads();

    // ---- one VI step: v_DST = max_o( qr[o] + conv3x3(v_SRC, w[o]) ) ----
#define STEP(SRC, DST)                                                          \
    do {                                                                        \
        float p0 = SRC[tl],          p1 = SRC[tl + 1],          p2 = SRC[tl + 2];          \
        float p3 = SRC[tl + PW],     p4 = SRC[tl + PW + 1],     p5 = SRC[tl + PW + 2];     \
        float p6 = SRC[tl + 2 * PW], p7 = SRC[tl + 2 * PW + 1], p8 = SRC[tl + 2 * PW + 2]; \
        float vm = -1e30f;                                                      \
        _Pragma("unroll")                                                       \
        for (int o = 0; o < 64; ++o) {                                          \
            float acc = qr[o];                                                  \
            acc += w[o * 9 + 0] * p0; acc += w[o * 9 + 1] * p1; acc += w[o * 9 + 2] * p2; \
            acc += w[o * 9 + 3] * p3; acc += w[o * 9 + 4] * p4; acc += w[o * 9 + 5] * p5; \
            acc += w[o * 9 + 6] * p6; acc += w[o * 9 + 7] * p7; acc += w[o * 9 + 8] * p8; \
            vm = fmaxf(vm, acc);                                                \
        }                                                                       \
        DST[ctr] = vm;                                                          \
        __syncthreads();                                                        \
    } while (0)

    // 39 steps total; keep the outer loop ROLLED (code size << I$).
#pragma unroll 1
    for (int i = 0; i < 19; ++i) {
        STEP(vb0, vb1);
        STEP(vb1, vb0);
    }
    STEP(vb0, vb1);   // 39th step; latest v now in vb1

    // ---- final q = qr + conv3x3(v, w) (no channel max) ----
    {
        float p0 = vb1[tl],          p1 = vb1[tl + 1],          p2 = vb1[tl + 2];
        float p3 = vb1[tl + PW],     p4 = vb1[tl + PW + 1],     p5 = vb1[tl + PW + 2];
        float p6 = vb1[tl + 2 * PW], p7 = vb1[tl + 2 * PW + 1], p8 = vb1[tl + 2 * PW + 2];
#pragma unroll
        for (int o = 0; o < 64; ++o) {
            float acc = qr[o];
            acc += w[o * 9 + 0] * p0; acc += w[o * 9 + 1] * p1; acc += w[o * 9 + 2] * p2;
            acc += w[o * 9 + 3] * p3; acc += w[o * 9 + 4] * p4; acc += w[o * 9 + 5] * p5;
            acc += w[o * 9 + 6] * p6; acc += w[o * 9 + 7] * p7; acc += w[o * 9 + 8] * p8;
            qr[o] = acc;
        }
    }

    // ---- gather 3x3 neighborhood at (s2, s1) ----
    float s1v = S1[b], s2v = S2[b];
    int s1g = (int)floorf(s1v);
    s1g = min(max(s1g, 0), IMG - 1);
    int s2g = IMG - 1 - (int)floorf(s2v);
    s2g = min(max(s2g, 0), IMG - 1);
    int s1i[3] = {max(s1g - 1, 0), s1g, min(s1g + 1, IMG - 1)};
    int s2i[3] = {max(s2g - 1, 0), s2g, min(s2g + 1, IMG - 1)};
#pragma unroll
    for (int i = 0; i < 3; ++i)
#pragma unroll
        for (int j = 0; j < 3; ++j)
            if (x == s1i[i] && y == s2i[j]) {
#pragma unroll
                for (int o = 0; o < 64; ++o)
                    vout[(i * 3 + j) * 64 + o] = qr[o];
            }
    if (t == 0) {
        vout[576] = s1v;
        vout[577] = s2v;
        vout[578] = gamma[b];
    }
    __syncthreads();

    // ---- MLP: 579 -> 100 -> 50 -> 1 ----
    if (t < 100) {
        float acc = 0.f;
        for (int k2 = 0; k2 < 579; ++k2)
            acc += fc1[t * 579 + k2] * vout[k2];
        l1[t] = fmaxf(acc, 0.f);
    }
    __syncthreads();
    if (t < 50) {
        float acc = 0.f;
        for (int k2 = 0; k2 < 100; ++k2)
            acc += fc2[t * 100 + k2] * l1[k2];
        l2[t] = fmaxf(acc, 0.f);
    }
    __syncthreads();
    if (t == 0) {
        float acc = 0.f;
        for (int k2 = 0; k2 < 50; ++k2)
            acc += fc3[k2] * l2[k2];
        out[b] = acc;
    }
}

extern "C" void kernel_launch(void* const* d_in, const int* in_sizes, int n_in,
                              void* d_out, int out_size, void* d_ws, size_t ws_size,
                              hipStream_t stream) {
    const float* X     = (const float*)d_in[0];
    const float* S1    = (const float*)d_in[1];
    const float* S2    = (const float*)d_in[2];
    const float* gamma = (const float*)d_in[3];
    const float* h_w   = (const float*)d_in[4];
    const float* h_b   = (const float*)d_in[5];
    const float* r_w   = (const float*)d_in[6];
    const float* q_w   = (const float*)d_in[7];
    const float* w     = (const float*)d_in[8];
    const float* fc1   = (const float*)d_in[9];
    const float* fc2   = (const float*)d_in[10];
    const float* fc3   = (const float*)d_in[11];
    float* weff = (float*)d_ws;
    float* outp = (float*)d_out;

    prep_kernel<<<1, 64, 0, stream>>>(h_w, h_b, r_w, weff);
    vin_kernel<<<NB, 256, 0, stream>>>(X, S1, S2, gamma, q_w, w, fc1, fc2, fc3,
                                       weff, outp);
}